// Round 1
// baseline (1918.818 us; speedup 1.0000x reference)
//
#include <hip/hip_runtime.h>

#define N_NODES 100000
#define E_EDGES 1600000
#define F_IN    256
#define F_HID   64
#define F_OUT   16

// ---------------------------------------------------------------------------
// K1: support1[N,64] = x[N,256] @ W1[256,64]
// Block: 256 threads -> 64 rows x 64 cols tile. Thread = 4 rows x 4 cols.
// W1 staged in LDS in k-chunks of 64 (16 KB). x read straight from global:
// within a wave, the 16 lanes of a col-group share the x address -> broadcast.
// ---------------------------------------------------------------------------
__global__ __launch_bounds__(256) void gemm1_kernel(const float* __restrict__ x,
                                                    const float* __restrict__ W1,
                                                    float* __restrict__ support1) {
    __shared__ __align__(16) float Ws[64 * 64];   // 16 KB chunk of W1
    const int t  = threadIdx.x;
    const int rg = t >> 4;    // 0..15 row group
    const int cg = t & 15;    // 0..15 col group
    const int r0 = blockIdx.x * 64 + rg * 4;

    // Clamped row pointers (guard at store time; clamped loads stay finite)
    const float* xp[4];
#pragma unroll
    for (int r = 0; r < 4; ++r) {
        int row = r0 + r;
        if (row > N_NODES - 1) row = N_NODES - 1;
        xp[r] = x + (size_t)row * F_IN;
    }

    float acc[4][4] = {};

    for (int kb = 0; kb < F_IN; kb += 64) {
        // stage W1[kb..kb+63][0..63] into LDS
#pragma unroll
        for (int i = 0; i < 4; ++i) {
            int f  = t + i * 256;          // 0..1023 float4 id
            int kr = f >> 4;               // k row 0..63
            int cq = f & 15;               // col quad
            *(float4*)&Ws[kr * 64 + cq * 4] =
                *(const float4*)&W1[(size_t)(kb + kr) * F_HID + cq * 4];
        }
        __syncthreads();

#pragma unroll 4
        for (int k = 0; k < 64; k += 4) {
            float4 wv[4];
#pragma unroll
            for (int kk = 0; kk < 4; ++kk)
                wv[kk] = *(const float4*)&Ws[(k + kk) * 64 + cg * 4];
#pragma unroll
            for (int r = 0; r < 4; ++r) {
                float4 xv = *(const float4*)(xp[r] + kb + k);
                float xvf[4] = {xv.x, xv.y, xv.z, xv.w};
#pragma unroll
                for (int kk = 0; kk < 4; ++kk) {
                    const float* wp = (const float*)&wv[kk];
#pragma unroll
                    for (int c = 0; c < 4; ++c)
                        acc[r][c] = fmaf(xvf[kk], wp[c], acc[r][c]);
                }
            }
        }
        __syncthreads();
    }

#pragma unroll
    for (int r = 0; r < 4; ++r) {
        int row = r0 + r;
        if (row < N_NODES)
            *(float4*)&support1[(size_t)row * F_HID + cg * 4] =
                make_float4(acc[r][0], acc[r][1], acc[r][2], acc[r][3]);
    }
}

// ---------------------------------------------------------------------------
// K2: spmm1 — acc1[dst] += w * support1[src], F=64.
// 16 lanes per edge, float4 per lane, fp32 global atomics.
// ---------------------------------------------------------------------------
__global__ __launch_bounds__(256) void spmm1_kernel(const int* __restrict__ esrc,
                                                    const int* __restrict__ edst,
                                                    const float* __restrict__ evals,
                                                    const float* __restrict__ support1,
                                                    float* __restrict__ acc1) {
    const int t = threadIdx.x;
    const int e = blockIdx.x * 16 + (t >> 4);
    const int j = (t & 15) * 4;
    const int s = esrc[e];
    const int d = edst[e];
    const float w = evals[e];
    float4 v = *(const float4*)&support1[(size_t)s * F_HID + j];
    float* out = &acc1[(size_t)d * F_HID + j];
    atomicAdd(out + 0, w * v.x);
    atomicAdd(out + 1, w * v.y);
    atomicAdd(out + 2, w * v.z);
    atomicAdd(out + 3, w * v.w);
}

// ---------------------------------------------------------------------------
// K3: support2[N,16] = relu(acc1 + b1) @ W2[64,16]
// 16 lanes per row (one per output col), 16 rows per block.
// ---------------------------------------------------------------------------
__global__ __launch_bounds__(256) void gemm2_kernel(const float* __restrict__ acc1,
                                                    const float* __restrict__ b1,
                                                    const float* __restrict__ W2,
                                                    float* __restrict__ support2) {
    __shared__ __align__(16) float W2t[16][68];   // W2 transposed, padded
    __shared__ __align__(16) float b1s[64];
    const int t = threadIdx.x;
    if (t < 64) b1s[t] = b1[t];
    for (int i = t; i < 64 * 16; i += 256) {
        int k = i >> 4, c = i & 15;
        W2t[c][k] = W2[i];
    }
    __syncthreads();

    const int row = blockIdx.x * 16 + (t >> 4);
    const int j   = t & 15;
    float acc = 0.f;
#pragma unroll
    for (int k = 0; k < 64; k += 4) {
        float4 xv = *(const float4*)&acc1[(size_t)row * F_HID + k];
        float4 bv = *(const float4*)&b1s[k];
        float4 wv = *(const float4*)&W2t[j][k];
        float h0 = fmaxf(xv.x + bv.x, 0.f);
        float h1 = fmaxf(xv.y + bv.y, 0.f);
        float h2 = fmaxf(xv.z + bv.z, 0.f);
        float h3 = fmaxf(xv.w + bv.w, 0.f);
        acc = fmaf(h0, wv.x, acc);
        acc = fmaf(h1, wv.y, acc);
        acc = fmaf(h2, wv.z, acc);
        acc = fmaf(h3, wv.w, acc);
    }
    support2[(size_t)row * F_OUT + j] = acc;
}

// ---------------------------------------------------------------------------
// K4: spmm2 — logits[dst] += w * support2[src], F=16.
// 4 lanes per edge, float4 per lane.
// ---------------------------------------------------------------------------
__global__ __launch_bounds__(256) void spmm2_kernel(const int* __restrict__ esrc,
                                                    const int* __restrict__ edst,
                                                    const float* __restrict__ evals,
                                                    const float* __restrict__ support2,
                                                    float* __restrict__ logits) {
    const int t = threadIdx.x;
    const int e = blockIdx.x * 64 + (t >> 2);
    const int j = (t & 3) * 4;
    const int s = esrc[e];
    const int d = edst[e];
    const float w = evals[e];
    float4 v = *(const float4*)&support2[(size_t)s * F_OUT + j];
    float* out = &logits[(size_t)d * F_OUT + j];
    atomicAdd(out + 0, w * v.x);
    atomicAdd(out + 1, w * v.y);
    atomicAdd(out + 2, w * v.z);
    atomicAdd(out + 3, w * v.w);
}

// ---------------------------------------------------------------------------
// K5: out = log_softmax(out + b2) per row of 16, in place.
// 16 lanes per row; shuffle reductions at width 16.
// ---------------------------------------------------------------------------
__global__ __launch_bounds__(256) void lsm_kernel(const float* __restrict__ b2,
                                                  float* __restrict__ out) {
    const int t   = threadIdx.x;
    const int row = blockIdx.x * 16 + (t >> 4);
    const int j   = t & 15;
    float v = out[(size_t)row * F_OUT + j] + b2[j];
    float m = v;
#pragma unroll
    for (int off = 8; off > 0; off >>= 1)
        m = fmaxf(m, __shfl_xor(m, off, 16));
    float ex = __expf(v - m);
    float s = ex;
#pragma unroll
    for (int off = 8; off > 0; off >>= 1)
        s += __shfl_xor(s, off, 16);
    out[(size_t)row * F_OUT + j] = v - m - __logf(s);
}

// ---------------------------------------------------------------------------
extern "C" void kernel_launch(void* const* d_in, const int* in_sizes, int n_in,
                              void* d_out, int out_size, void* d_ws, size_t ws_size,
                              hipStream_t stream) {
    const float* x     = (const float*)d_in[0];
    const int*   esrc  = (const int*)  d_in[1];
    const int*   edst  = (const int*)  d_in[2];
    const float* evals = (const float*)d_in[3];
    const float* W1    = (const float*)d_in[4];
    const float* b1    = (const float*)d_in[5];
    const float* W2    = (const float*)d_in[6];
    const float* b2    = (const float*)d_in[7];
    float* out = (float*)d_out;

    float* support1 = (float*)d_ws;                        // N*64
    float* acc1     = support1 + (size_t)N_NODES * F_HID;  // N*64
    float* support2 = acc1     + (size_t)N_NODES * F_HID;  // N*16

    hipMemsetAsync(acc1, 0, (size_t)N_NODES * F_HID * sizeof(float), stream);
    hipMemsetAsync(out,  0, (size_t)N_NODES * F_OUT * sizeof(float), stream);

    gemm1_kernel<<<(N_NODES + 63) / 64, 256, 0, stream>>>(x, W1, support1);
    spmm1_kernel<<<E_EDGES / 16, 256, 0, stream>>>(esrc, edst, evals, support1, acc1);
    gemm2_kernel<<<N_NODES / 16, 256, 0, stream>>>(acc1, b1, W2, support2);
    spmm2_kernel<<<E_EDGES / 64, 256, 0, stream>>>(esrc, edst, evals, support2, out);
    lsm_kernel<<<N_NODES / 16, 256, 0, stream>>>(b2, out);
}

// Round 2
// 564.291 us; speedup vs baseline: 3.4004x; 3.4004x over previous
//
#include <hip/hip_runtime.h>

#define N_NODES 100000
#define E_EDGES 1600000
#define F_IN    256
#define F_HID   64
#define F_OUT   16
#define SCAN_BLOCKS 98   // ceil(100000/1024)

// ---------------------------------------------------------------------------
// K1: support1[N,64] = x[N,256] @ W1[256,64]   (unchanged from round 1)
// ---------------------------------------------------------------------------
__global__ __launch_bounds__(256) void gemm1_kernel(const float* __restrict__ x,
                                                    const float* __restrict__ W1,
                                                    float* __restrict__ support1) {
    __shared__ __align__(16) float Ws[64 * 64];
    const int t  = threadIdx.x;
    const int rg = t >> 4;
    const int cg = t & 15;
    const int r0 = blockIdx.x * 64 + rg * 4;

    const float* xp[4];
#pragma unroll
    for (int r = 0; r < 4; ++r) {
        int row = r0 + r;
        if (row > N_NODES - 1) row = N_NODES - 1;
        xp[r] = x + (size_t)row * F_IN;
    }

    float acc[4][4] = {};

    for (int kb = 0; kb < F_IN; kb += 64) {
#pragma unroll
        for (int i = 0; i < 4; ++i) {
            int f  = t + i * 256;
            int kr = f >> 4;
            int cq = f & 15;
            *(float4*)&Ws[kr * 64 + cq * 4] =
                *(const float4*)&W1[(size_t)(kb + kr) * F_HID + cq * 4];
        }
        __syncthreads();

#pragma unroll 4
        for (int k = 0; k < 64; k += 4) {
            float4 wv[4];
#pragma unroll
            for (int kk = 0; kk < 4; ++kk)
                wv[kk] = *(const float4*)&Ws[(k + kk) * 64 + cg * 4];
#pragma unroll
            for (int r = 0; r < 4; ++r) {
                float4 xv = *(const float4*)(xp[r] + kb + k);
                float xvf[4] = {xv.x, xv.y, xv.z, xv.w};
#pragma unroll
                for (int kk = 0; kk < 4; ++kk) {
                    const float* wp = (const float*)&wv[kk];
#pragma unroll
                    for (int c = 0; c < 4; ++c)
                        acc[r][c] = fmaf(xvf[kk], wp[c], acc[r][c]);
                }
            }
        }
        __syncthreads();
    }

#pragma unroll
    for (int r = 0; r < 4; ++r) {
        int row = r0 + r;
        if (row < N_NODES)
            *(float4*)&support1[(size_t)row * F_HID + cg * 4] =
                make_float4(acc[r][0], acc[r][1], acc[r][2], acc[r][3]);
    }
}

// ---------------------------------------------------------------------------
// CSR build: histogram -> exclusive scan -> scatter (counting sort by dst)
// ---------------------------------------------------------------------------
__global__ __launch_bounds__(256) void hist_kernel(const int* __restrict__ edst,
                                                   int* __restrict__ deg) {
    const int e = blockIdx.x * 256 + threadIdx.x;
    atomicAdd(&deg[edst[e]], 1);
}

// Block-level scan: 1024 elements per block (4 per thread), Hillis-Steele in LDS.
__global__ __launch_bounds__(256) void scan1_kernel(const int* __restrict__ deg,
                                                    int* __restrict__ rowstart,
                                                    int* __restrict__ bsums) {
    __shared__ int s[256];
    const int t = threadIdx.x;
    const int base = blockIdx.x * 1024 + t * 4;
    int v[4], sum = 0;
#pragma unroll
    for (int r = 0; r < 4; ++r) {
        v[r] = (base + r < N_NODES) ? deg[base + r] : 0;
        sum += v[r];
    }
    s[t] = sum;
    __syncthreads();
#pragma unroll
    for (int off = 1; off < 256; off <<= 1) {
        int y = (t >= off) ? s[t - off] : 0;
        __syncthreads();
        s[t] += y;
        __syncthreads();
    }
    int run = s[t] - sum;   // exclusive prefix within block
#pragma unroll
    for (int r = 0; r < 4; ++r) {
        if (base + r < N_NODES) rowstart[base + r] = run;
        run += v[r];
    }
    if (t == 255) bsums[blockIdx.x] = s[255];
}

__global__ __launch_bounds__(128) void scan2_kernel(int* __restrict__ bsums) {
    __shared__ int s[128];
    const int t = threadIdx.x;
    int v = (t < SCAN_BLOCKS) ? bsums[t] : 0;
    s[t] = v;
    __syncthreads();
#pragma unroll
    for (int off = 1; off < 128; off <<= 1) {
        int y = (t >= off) ? s[t - off] : 0;
        __syncthreads();
        s[t] += y;
        __syncthreads();
    }
    if (t < SCAN_BLOCKS) bsums[t] = s[t] - v;   // exclusive
}

__global__ __launch_bounds__(256) void scan3_kernel(int* __restrict__ rowstart,
                                                    const int* __restrict__ bsums) {
    const int t = threadIdx.x;
    const int base = blockIdx.x * 1024 + t * 4;
    const int add = bsums[blockIdx.x];
#pragma unroll
    for (int r = 0; r < 4; ++r)
        if (base + r < N_NODES) rowstart[base + r] += add;
}

__global__ __launch_bounds__(256) void scatter_kernel(const int* __restrict__ esrc,
                                                      const int* __restrict__ edst,
                                                      const float* __restrict__ evals,
                                                      const int* __restrict__ rowstart,
                                                      int* __restrict__ cursor,
                                                      int* __restrict__ sorted_src,
                                                      float* __restrict__ sorted_val) {
    const int e = blockIdx.x * 256 + threadIdx.x;
    const int d = edst[e];
    const int p = rowstart[d] + atomicAdd(&cursor[d], 1);
    sorted_src[p] = esrc[e];
    sorted_val[p] = evals[e];
}

// ---------------------------------------------------------------------------
// K2 fused: per dst node (one 64-lane wave): h = relu(sum_e w*support1[src] + b1),
// then support2[node] = h @ W2.  No atomics; one write per output element.
// ---------------------------------------------------------------------------
__global__ __launch_bounds__(256) void spmm1_fused_kernel(const int* __restrict__ rowstart,
                                                          const int* __restrict__ deg,
                                                          const int* __restrict__ sorted_src,
                                                          const float* __restrict__ sorted_val,
                                                          const float* __restrict__ support1,
                                                          const float* __restrict__ b1,
                                                          const float* __restrict__ W2,
                                                          float* __restrict__ support2) {
    __shared__ float W2s[64 * 16];
    __shared__ float b1s[64];
    __shared__ float hs[4][64];
    const int t = threadIdx.x;
#pragma unroll
    for (int i = 0; i < 4; ++i) W2s[t + i * 256] = W2[t + i * 256];
    if (t < 64) b1s[t] = b1[t];
    __syncthreads();

    const int wave = t >> 6;
    const int lane = t & 63;
    const int node = blockIdx.x * 4 + wave;   // grid exact: 25000*4 = 100000

    const int beg = rowstart[node];
    const int cnt = deg[node];

    // Preload up to 64 edge (src,val) pairs into the wave's registers.
    int   src_l = 0;
    float val_l = 0.f;
    if (lane < cnt) {
        src_l = sorted_src[beg + lane];
        val_l = sorted_val[beg + lane];
    }

    float acc = 0.f;
    const int kmax = cnt < 64 ? cnt : 64;
    for (int k = 0; k < kmax; ++k) {
        int   s = __shfl(src_l, k);
        float w = __shfl(val_l, k);
        acc = fmaf(w, support1[(size_t)s * F_HID + lane], acc);
    }
    for (int k = 64; k < cnt; ++k) {            // vanishingly rare (Poisson 16)
        int   s = sorted_src[beg + k];
        float w = sorted_val[beg + k];
        acc = fmaf(w, support1[(size_t)s * F_HID + lane], acc);
    }

    hs[wave][lane] = fmaxf(acc + b1s[lane], 0.f);
    __syncthreads();

    if (lane < 16) {
        float o = 0.f;
#pragma unroll
        for (int k = 0; k < 64; ++k)
            o = fmaf(hs[wave][k], W2s[k * 16 + lane], o);
        support2[(size_t)node * F_OUT + lane] = o;
    }
}

// ---------------------------------------------------------------------------
// K3 fused: per dst node (16 lanes): logits = sum_e w*support2[src] + b2,
// then log_softmax in-register.  Writes d_out exactly once per element.
// ---------------------------------------------------------------------------
__global__ __launch_bounds__(256) void spmm2_fused_kernel(const int* __restrict__ rowstart,
                                                          const int* __restrict__ deg,
                                                          const int* __restrict__ sorted_src,
                                                          const float* __restrict__ sorted_val,
                                                          const float* __restrict__ support2,
                                                          const float* __restrict__ b2,
                                                          float* __restrict__ out) {
    __shared__ float b2s[16];
    const int t = threadIdx.x;
    if (t < 16) b2s[t] = b2[t];
    __syncthreads();

    const int j    = t & 15;
    const int node = blockIdx.x * 16 + (t >> 4);   // grid exact: 6250*16 = 100000

    const int beg = rowstart[node];
    const int cnt = deg[node];

    // Preload 2 batches of 16 edges -> covers cnt<=32 (P(cnt>32) ~ 1e-4).
    int   src_a = 0, src_b = 0;
    float val_a = 0.f, val_b = 0.f;
    if (j < cnt)      { src_a = sorted_src[beg + j];      val_a = sorted_val[beg + j]; }
    if (j + 16 < cnt) { src_b = sorted_src[beg + 16 + j]; val_b = sorted_val[beg + 16 + j]; }

    float acc = 0.f;
    const int k1 = cnt < 16 ? cnt : 16;
    for (int k = 0; k < k1; ++k) {
        int   s = __shfl(src_a, k, 16);
        float w = __shfl(val_a, k, 16);
        acc = fmaf(w, support2[(size_t)s * F_OUT + j], acc);
    }
    const int k2 = cnt < 32 ? cnt : 32;
    for (int k = 16; k < k2; ++k) {
        int   s = __shfl(src_b, k - 16, 16);
        float w = __shfl(val_b, k - 16, 16);
        acc = fmaf(w, support2[(size_t)s * F_OUT + j], acc);
    }
    for (int k = 32; k < cnt; ++k) {
        int   s = sorted_src[beg + k];
        float w = sorted_val[beg + k];
        acc = fmaf(w, support2[(size_t)s * F_OUT + j], acc);
    }

    float v = acc + b2s[j];
    float m = v;
#pragma unroll
    for (int off = 8; off > 0; off >>= 1)
        m = fmaxf(m, __shfl_xor(m, off, 16));
    float ex = __expf(v - m);
    float sum = ex;
#pragma unroll
    for (int off = 8; off > 0; off >>= 1)
        sum += __shfl_xor(sum, off, 16);
    out[(size_t)node * F_OUT + j] = v - m - __logf(sum);
}

// ---------------------------------------------------------------------------
extern "C" void kernel_launch(void* const* d_in, const int* in_sizes, int n_in,
                              void* d_out, int out_size, void* d_ws, size_t ws_size,
                              hipStream_t stream) {
    const float* x     = (const float*)d_in[0];
    const int*   esrc  = (const int*)  d_in[1];
    const int*   edst  = (const int*)  d_in[2];
    const float* evals = (const float*)d_in[3];
    const float* W1    = (const float*)d_in[4];
    const float* b1    = (const float*)d_in[5];
    const float* W2    = (const float*)d_in[6];
    const float* b2    = (const float*)d_in[7];
    float* out = (float*)d_out;

    // Workspace layout (~45.6 MB)
    float* support1   = (float*)d_ws;                       // N*64
    float* support2   = support1 + (size_t)N_NODES * F_HID; // N*16
    int*   sorted_src = (int*)(support2 + (size_t)N_NODES * F_OUT); // E
    float* sorted_val = (float*)(sorted_src + E_EDGES);     // E
    int*   rowstart   = (int*)(sorted_val + E_EDGES);       // N
    int*   deg        = rowstart + N_NODES;                 // N (hist, then cursor)
    int*   bsums      = deg + N_NODES;                      // SCAN_BLOCKS

    // --- CSR build ---
    hipMemsetAsync(deg, 0, (size_t)N_NODES * sizeof(int), stream);
    hist_kernel<<<E_EDGES / 256, 256, 0, stream>>>(edst, deg);
    scan1_kernel<<<SCAN_BLOCKS, 256, 0, stream>>>(deg, rowstart, bsums);
    scan2_kernel<<<1, 128, 0, stream>>>(bsums);
    scan3_kernel<<<SCAN_BLOCKS, 256, 0, stream>>>(rowstart, bsums);
    hipMemsetAsync(deg, 0, (size_t)N_NODES * sizeof(int), stream);
    scatter_kernel<<<E_EDGES / 256, 256, 0, stream>>>(esrc, edst, evals, rowstart, deg,
                                                      sorted_src, sorted_val);

    // --- dense + sparse pipeline ---
    gemm1_kernel<<<(N_NODES + 63) / 64, 256, 0, stream>>>(x, W1, support1);
    spmm1_fused_kernel<<<N_NODES / 4, 256, 0, stream>>>(rowstart, deg, sorted_src, sorted_val,
                                                        support1, b1, W2, support2);
    spmm2_fused_kernel<<<N_NODES / 16, 256, 0, stream>>>(rowstart, deg, sorted_src, sorted_val,
                                                         support2, b2, out);
}

// Round 3
// 448.741 us; speedup vs baseline: 4.2760x; 1.2575x over previous
//
#include <hip/hip_runtime.h>
#include <hip/hip_fp16.h>

#define N_NODES 100000
#define E_EDGES 1600000
#define F_IN    256
#define F_HID   64
#define F_OUT   16
#define SCAN_BLOCKS 98        // ceil(100000/1024)
#define GEMM1_BLOCKS 1563     // ceil(100000/64)
#define HIST_BLOCKS  6250     // 1600000/256

// ---------------------------------------------------------------------------
// K1 (fused): blocks [0,GEMM1_BLOCKS) compute support1[N,64] = x @ W1 (fp16 out);
// blocks [GEMM1_BLOCKS, +HIST_BLOCKS) do the degree histogram (overlaps the
// atomic latency with gemm VALU work).
// ---------------------------------------------------------------------------
__global__ __launch_bounds__(256) void gemm1_hist_kernel(const float* __restrict__ x,
                                                         const float* __restrict__ W1,
                                                         __half* __restrict__ support1,
                                                         const int* __restrict__ edst,
                                                         int* __restrict__ deg) {
    if (blockIdx.x >= GEMM1_BLOCKS) {
        const int e = (blockIdx.x - GEMM1_BLOCKS) * 256 + threadIdx.x;
        atomicAdd(&deg[edst[e]], 1);
        return;
    }

    __shared__ __align__(16) float Ws[64 * 64];
    const int t  = threadIdx.x;
    const int rg = t >> 4;
    const int cg = t & 15;
    const int r0 = blockIdx.x * 64 + rg * 4;

    const float* xp[4];
#pragma unroll
    for (int r = 0; r < 4; ++r) {
        int row = r0 + r;
        if (row > N_NODES - 1) row = N_NODES - 1;
        xp[r] = x + (size_t)row * F_IN;
    }

    float acc[4][4] = {};

    for (int kb = 0; kb < F_IN; kb += 64) {
#pragma unroll
        for (int i = 0; i < 4; ++i) {
            int f  = t + i * 256;
            int kr = f >> 4;
            int cq = f & 15;
            *(float4*)&Ws[kr * 64 + cq * 4] =
                *(const float4*)&W1[(size_t)(kb + kr) * F_HID + cq * 4];
        }
        __syncthreads();

#pragma unroll 4
        for (int k = 0; k < 64; k += 4) {
            float4 wv[4];
#pragma unroll
            for (int kk = 0; kk < 4; ++kk)
                wv[kk] = *(const float4*)&Ws[(k + kk) * 64 + cg * 4];
#pragma unroll
            for (int r = 0; r < 4; ++r) {
                float4 xv = *(const float4*)(xp[r] + kb + k);
                float xvf[4] = {xv.x, xv.y, xv.z, xv.w};
#pragma unroll
                for (int kk = 0; kk < 4; ++kk) {
                    const float* wp = (const float*)&wv[kk];
#pragma unroll
                    for (int c = 0; c < 4; ++c)
                        acc[r][c] = fmaf(xvf[kk], wp[c], acc[r][c]);
                }
            }
        }
        __syncthreads();
    }

#pragma unroll
    for (int r = 0; r < 4; ++r) {
        int row = r0 + r;
        if (row < N_NODES) {
            union { __half2 h2[2]; uint2 u; } pk;
            pk.h2[0] = __floats2half2_rn(acc[r][0], acc[r][1]);
            pk.h2[1] = __floats2half2_rn(acc[r][2], acc[r][3]);
            *(uint2*)&support1[(size_t)row * F_HID + cg * 4] = pk.u;
        }
    }
}

// ---------------------------------------------------------------------------
// CSR build: exclusive scan over degrees, then scatter into interleaved int2.
// ---------------------------------------------------------------------------
__global__ __launch_bounds__(256) void scan1_kernel(const int* __restrict__ deg,
                                                    int* __restrict__ rowstart,
                                                    int* __restrict__ bsums) {
    __shared__ int s[256];
    const int t = threadIdx.x;
    const int base = blockIdx.x * 1024 + t * 4;
    int v[4], sum = 0;
#pragma unroll
    for (int r = 0; r < 4; ++r) {
        v[r] = (base + r < N_NODES) ? deg[base + r] : 0;
        sum += v[r];
    }
    s[t] = sum;
    __syncthreads();
#pragma unroll
    for (int off = 1; off < 256; off <<= 1) {
        int y = (t >= off) ? s[t - off] : 0;
        __syncthreads();
        s[t] += y;
        __syncthreads();
    }
    int run = s[t] - sum;
#pragma unroll
    for (int r = 0; r < 4; ++r) {
        if (base + r < N_NODES) rowstart[base + r] = run;
        run += v[r];
    }
    if (t == 255) bsums[blockIdx.x] = s[255];
}

__global__ __launch_bounds__(128) void scan2_kernel(int* __restrict__ bsums) {
    __shared__ int s[128];
    const int t = threadIdx.x;
    int v = (t < SCAN_BLOCKS) ? bsums[t] : 0;
    s[t] = v;
    __syncthreads();
#pragma unroll
    for (int off = 1; off < 128; off <<= 1) {
        int y = (t >= off) ? s[t - off] : 0;
        __syncthreads();
        s[t] += y;
        __syncthreads();
    }
    if (t < SCAN_BLOCKS) bsums[t] = s[t] - v;
}

__global__ __launch_bounds__(256) void scan3_kernel(int* __restrict__ rowstart,
                                                    const int* __restrict__ bsums) {
    const int t = threadIdx.x;
    const int base = blockIdx.x * 1024 + t * 4;
    const int add = bsums[blockIdx.x];
#pragma unroll
    for (int r = 0; r < 4; ++r)
        if (base + r < N_NODES) rowstart[base + r] += add;
}

__global__ __launch_bounds__(256) void scatter_kernel(const int* __restrict__ esrc,
                                                      const int* __restrict__ edst,
                                                      const float* __restrict__ evals,
                                                      const int* __restrict__ rowstart,
                                                      int* __restrict__ cursor,
                                                      int2* __restrict__ sorted_edges) {
    const int e = blockIdx.x * 256 + threadIdx.x;
    const int d = edst[e];
    const int p = rowstart[d] + atomicAdd(&cursor[d], 1);
    sorted_edges[p] = make_int2(esrc[e], __float_as_int(evals[e]));
}

// ---------------------------------------------------------------------------
// K2 fused: per dst node (one wave): h = relu(sum_e w*support1[src] + b1),
// support2[node] = h @ W2 (fp16 out).  8-edge ILP batches.
// ---------------------------------------------------------------------------
__global__ __launch_bounds__(256) void spmm1_fused_kernel(const int* __restrict__ rowstart,
                                                          const int* __restrict__ deg,
                                                          const int2* __restrict__ sorted_edges,
                                                          const __half* __restrict__ support1,
                                                          const float* __restrict__ b1,
                                                          const float* __restrict__ W2,
                                                          __half* __restrict__ support2) {
    __shared__ float W2s[64 * 16];
    __shared__ float b1s[64];
    __shared__ float hs[4][64];
    const int t = threadIdx.x;
#pragma unroll
    for (int i = 0; i < 4; ++i) W2s[t + i * 256] = W2[t + i * 256];
    if (t < 64) b1s[t] = b1[t];
    __syncthreads();

    const int wave = t >> 6;
    const int lane = t & 63;
    const int node = blockIdx.x * 4 + wave;   // grid exact: 25000*4

    const int beg = rowstart[node];
    const int cnt = deg[node];

    int   src_l = 0;
    float val_l = 0.f;
    if (lane < cnt) {
        int2 ev = sorted_edges[beg + lane];
        src_l = ev.x;
        val_l = __int_as_float(ev.y);
    }

    float acc = 0.f;
    const int kmax = cnt < 64 ? cnt : 64;
    int k = 0;
    for (; k + 8 <= kmax; k += 8) {
        float f[8], w[8];
#pragma unroll
        for (int u = 0; u < 8; ++u) {
            int s = __shfl(src_l, k + u);
            w[u]  = __shfl(val_l, k + u);
            f[u]  = __half2float(support1[(size_t)s * F_HID + lane]);
        }
#pragma unroll
        for (int u = 0; u < 8; ++u) acc = fmaf(w[u], f[u], acc);
    }
    for (; k < kmax; ++k) {
        int   s = __shfl(src_l, k);
        float w = __shfl(val_l, k);
        acc = fmaf(w, __half2float(support1[(size_t)s * F_HID + lane]), acc);
    }
    for (k = 64; k < cnt; ++k) {              // vanishingly rare (Poisson 16)
        int2 ev = sorted_edges[beg + k];
        acc = fmaf(__int_as_float(ev.y),
                   __half2float(support1[(size_t)ev.x * F_HID + lane]), acc);
    }

    hs[wave][lane] = fmaxf(acc + b1s[lane], 0.f);
    __syncthreads();

    if (lane < 16) {
        float o = 0.f;
#pragma unroll
        for (int kk = 0; kk < 64; ++kk)
            o = fmaf(hs[wave][kk], W2s[kk * 16 + lane], o);
        support2[(size_t)node * F_OUT + lane] = __float2half(o);
    }
}

// ---------------------------------------------------------------------------
// K3 fused: per dst node (16 lanes): logits = sum_e w*support2[src] + b2,
// then log_softmax.  8-edge ILP batches; support2 fp16 (3.2 MB, L2-friendly).
// ---------------------------------------------------------------------------
__global__ __launch_bounds__(256) void spmm2_fused_kernel(const int* __restrict__ rowstart,
                                                          const int* __restrict__ deg,
                                                          const int2* __restrict__ sorted_edges,
                                                          const __half* __restrict__ support2,
                                                          const float* __restrict__ b2,
                                                          float* __restrict__ out) {
    __shared__ float b2s[16];
    const int t = threadIdx.x;
    if (t < 16) b2s[t] = b2[t];
    __syncthreads();

    const int j    = t & 15;
    const int node = blockIdx.x * 16 + (t >> 4);   // grid exact: 6250*16

    const int beg = rowstart[node];
    const int cnt = deg[node];

    int   src_a = 0, src_b = 0;
    float val_a = 0.f, val_b = 0.f;
    if (j < cnt)      { int2 ev = sorted_edges[beg + j];      src_a = ev.x; val_a = __int_as_float(ev.y); }
    if (j + 16 < cnt) { int2 ev = sorted_edges[beg + 16 + j]; src_b = ev.x; val_b = __int_as_float(ev.y); }

    float acc = 0.f;
    const int kmax2 = cnt < 32 ? cnt : 32;
    int k = 0;
    for (; k + 8 <= kmax2; k += 8) {           // batches never straddle 16
        float f[8], w[8];
#pragma unroll
        for (int u = 0; u < 8; ++u) {
            int kk = k + u;
            int   s = (k < 16) ? __shfl(src_a, kk, 16) : __shfl(src_b, kk - 16, 16);
            w[u]    = (k < 16) ? __shfl(val_a, kk, 16) : __shfl(val_b, kk - 16, 16);
            f[u]    = __half2float(support2[(size_t)s * F_OUT + j]);
        }
#pragma unroll
        for (int u = 0; u < 8; ++u) acc = fmaf(w[u], f[u], acc);
    }
    for (; k < kmax2; ++k) {
        int   s = (k < 16) ? __shfl(src_a, k, 16) : __shfl(src_b, k - 16, 16);
        float w = (k < 16) ? __shfl(val_a, k, 16) : __shfl(val_b, k - 16, 16);
        acc = fmaf(w, __half2float(support2[(size_t)s * F_OUT + j]), acc);
    }
    for (k = 32; k < cnt; ++k) {
        int2 ev = sorted_edges[beg + k];
        acc = fmaf(__int_as_float(ev.y),
                   __half2float(support2[(size_t)ev.x * F_OUT + j]), acc);
    }

    float v = acc + b2s[j];
    float m = v;
#pragma unroll
    for (int off = 8; off > 0; off >>= 1)
        m = fmaxf(m, __shfl_xor(m, off, 16));
    float ex = __expf(v - m);
    float sum = ex;
#pragma unroll
    for (int off = 8; off > 0; off >>= 1)
        sum += __shfl_xor(sum, off, 16);
    out[(size_t)node * F_OUT + j] = v - m - __logf(sum);
}

// ---------------------------------------------------------------------------
extern "C" void kernel_launch(void* const* d_in, const int* in_sizes, int n_in,
                              void* d_out, int out_size, void* d_ws, size_t ws_size,
                              hipStream_t stream) {
    const float* x     = (const float*)d_in[0];
    const int*   esrc  = (const int*)  d_in[1];
    const int*   edst  = (const int*)  d_in[2];
    const float* evals = (const float*)d_in[3];
    const float* W1    = (const float*)d_in[4];
    const float* b1    = (const float*)d_in[5];
    const float* W2    = (const float*)d_in[6];
    const float* b2    = (const float*)d_in[7];
    float* out = (float*)d_out;

    // Workspace layout (~30 MB)
    __half* support1     = (__half*)d_ws;                                // N*64 fp16
    __half* support2     = support1 + (size_t)N_NODES * F_HID;           // N*16 fp16
    int2*   sorted_edges = (int2*)(support2 + (size_t)N_NODES * F_OUT);  // E int2
    int*    rowstart     = (int*)(sorted_edges + E_EDGES);               // N
    int*    deg          = rowstart + N_NODES;                           // N (hist/cursor)
    int*    bsums        = deg + N_NODES;                                // SCAN_BLOCKS

    hipMemsetAsync(deg, 0, (size_t)N_NODES * sizeof(int), stream);
    // gemm1 + degree histogram in one launch (independent work, overlapped)
    gemm1_hist_kernel<<<GEMM1_BLOCKS + HIST_BLOCKS, 256, 0, stream>>>(x, W1, support1, edst, deg);
    scan1_kernel<<<SCAN_BLOCKS, 256, 0, stream>>>(deg, rowstart, bsums);
    scan2_kernel<<<1, 128, 0, stream>>>(bsums);
    scan3_kernel<<<SCAN_BLOCKS, 256, 0, stream>>>(rowstart, bsums);
    hipMemsetAsync(deg, 0, (size_t)N_NODES * sizeof(int), stream);
    scatter_kernel<<<E_EDGES / 256, 256, 0, stream>>>(esrc, edst, evals, rowstart, deg,
                                                      sorted_edges);
    spmm1_fused_kernel<<<N_NODES / 4, 256, 0, stream>>>(rowstart, deg, sorted_edges,
                                                        support1, b1, W2, support2);
    spmm2_fused_kernel<<<N_NODES / 16, 256, 0, stream>>>(rowstart, deg, sorted_edges,
                                                         support2, b2, out);
}

// Round 4
// 425.463 us; speedup vs baseline: 4.5100x; 1.0547x over previous
//
#include <hip/hip_runtime.h>
#include <hip/hip_fp16.h>

#define N_NODES 100000
#define E_EDGES 1600000
#define F_IN    256
#define F_HID   64
#define F_OUT   16
#define SCAN_BLOCKS 98        // ceil(100000/1024)
#define GEMM1_BLOCKS 782      // ceil(100000/128)
#define HIST_BLOCKS  6250     // 1600000/256

typedef _Float16 half8 __attribute__((ext_vector_type(8)));
typedef float    floatx4 __attribute__((ext_vector_type(4)));

// ---------------------------------------------------------------------------
// Prep: swizzle W1[256][64] fp32 -> f16 in exact MFMA B-fragment order:
// element (k,n) -> w1sw[((kb*4+nt)*64 + quad*16+ln)*8 + j]
//   kb=k>>5, quad=(k>>3)&3, j=k&7, nt=n>>4, ln=n&15
// so a lane's 8 B-frag halves are 16 contiguous bytes at lane*16.
// ---------------------------------------------------------------------------
__global__ __launch_bounds__(256) void w1_swizzle_kernel(const float* __restrict__ W1,
                                                         _Float16* __restrict__ w1sw) {
    const int i = blockIdx.x * 256 + threadIdx.x;   // 64 blocks -> 16384
    const int k = i >> 6, n = i & 63;
    const int kb = k >> 5, quad = (k >> 3) & 3, j = k & 7;
    const int nt = n >> 4, ln = n & 15;
    w1sw[((size_t)((kb * 4 + nt) * 64 + quad * 16 + ln)) * 8 + j] = (_Float16)W1[i];
}

// ---------------------------------------------------------------------------
// K1 (fused): blocks [0,GEMM1_BLOCKS): support1 = x @ W1 via MFMA f16
// (fp32 accumulate).  Blocks after that: degree histogram (overlapped).
// Per block: 128 rows; per wave: 32 rows (2 m-tiles) x 64 cols (4 n-tiles).
// ---------------------------------------------------------------------------
__global__ __launch_bounds__(256) void gemm1_hist_kernel(const float* __restrict__ x,
                                                         const _Float16* __restrict__ w1sw,
                                                         _Float16* __restrict__ support1,
                                                         const int* __restrict__ edst,
                                                         int* __restrict__ deg) {
    if (blockIdx.x >= GEMM1_BLOCKS) {
        const int e = (blockIdx.x - GEMM1_BLOCKS) * 256 + threadIdx.x;
        atomicAdd(&deg[edst[e]], 1);
        return;
    }

    __shared__ __align__(16) _Float16 Bs[8 * 4 * 64 * 8];   // 32 KB, frag-ordered
    const int t = threadIdx.x;

    // Stage pre-swizzled W1 into LDS, fully coalesced.
    {
        const float4* srcv = (const float4*)w1sw;   // 2048 float4
        float4*       dstv = (float4*)Bs;
#pragma unroll
        for (int i = 0; i < 8; ++i) dstv[t + i * 256] = srcv[t + i * 256];
    }
    __syncthreads();

    const int wave = t >> 6;
    const int lane = t & 63;
    const int ln   = lane & 15;
    const int quad = lane >> 4;
    const int row0 = blockIdx.x * 128 + wave * 32;

    // A-operand row pointers (2 m-tiles), clamped for the final partial block.
    const float* xp[2];
#pragma unroll
    for (int mt = 0; mt < 2; ++mt) {
        int r = row0 + mt * 16 + ln;
        if (r > N_NODES - 1) r = N_NODES - 1;
        xp[mt] = x + (size_t)r * F_IN + quad * 8;
    }

    floatx4 acc[2][4] = {};

#pragma unroll 4
    for (int kb = 0; kb < 8; ++kb) {
        half8 a[2];
#pragma unroll
        for (int mt = 0; mt < 2; ++mt) {
            float4 v0 = *(const float4*)(xp[mt] + kb * 32);
            float4 v1 = *(const float4*)(xp[mt] + kb * 32 + 4);
            half8 h;
            h[0] = (_Float16)v0.x; h[1] = (_Float16)v0.y;
            h[2] = (_Float16)v0.z; h[3] = (_Float16)v0.w;
            h[4] = (_Float16)v1.x; h[5] = (_Float16)v1.y;
            h[6] = (_Float16)v1.z; h[7] = (_Float16)v1.w;
            a[mt] = h;
        }
#pragma unroll
        for (int nt = 0; nt < 4; ++nt) {
            half8 b = *(const half8*)&Bs[((size_t)((kb * 4 + nt) * 64 + lane)) * 8];
            acc[0][nt] = __builtin_amdgcn_mfma_f32_16x16x32_f16(a[0], b, acc[0][nt], 0, 0, 0);
            acc[1][nt] = __builtin_amdgcn_mfma_f32_16x16x32_f16(a[1], b, acc[1][nt], 0, 0, 0);
        }
    }

    // Epilogue: C/D layout col=lane&15, row=quad*4+reg (verified m89).
#pragma unroll
    for (int mt = 0; mt < 2; ++mt) {
        const int rbase = row0 + mt * 16 + quad * 4;
#pragma unroll
        for (int r = 0; r < 4; ++r) {
            const int row = rbase + r;
            if (row < N_NODES) {
#pragma unroll
                for (int nt = 0; nt < 4; ++nt)
                    support1[(size_t)row * F_HID + nt * 16 + ln] = (_Float16)acc[mt][nt][r];
            }
        }
    }
}

// ---------------------------------------------------------------------------
// CSR build: exclusive scan over degrees, then scatter into interleaved int2.
// ---------------------------------------------------------------------------
__global__ __launch_bounds__(256) void scan1_kernel(const int* __restrict__ deg,
                                                    int* __restrict__ rowstart,
                                                    int* __restrict__ bsums) {
    __shared__ int s[256];
    const int t = threadIdx.x;
    const int base = blockIdx.x * 1024 + t * 4;
    int v[4], sum = 0;
#pragma unroll
    for (int r = 0; r < 4; ++r) {
        v[r] = (base + r < N_NODES) ? deg[base + r] : 0;
        sum += v[r];
    }
    s[t] = sum;
    __syncthreads();
#pragma unroll
    for (int off = 1; off < 256; off <<= 1) {
        int y = (t >= off) ? s[t - off] : 0;
        __syncthreads();
        s[t] += y;
        __syncthreads();
    }
    int run = s[t] - sum;
#pragma unroll
    for (int r = 0; r < 4; ++r) {
        if (base + r < N_NODES) rowstart[base + r] = run;
        run += v[r];
    }
    if (t == 255) bsums[blockIdx.x] = s[255];
}

__global__ __launch_bounds__(128) void scan2_kernel(int* __restrict__ bsums) {
    __shared__ int s[128];
    const int t = threadIdx.x;
    int v = (t < SCAN_BLOCKS) ? bsums[t] : 0;
    s[t] = v;
    __syncthreads();
#pragma unroll
    for (int off = 1; off < 128; off <<= 1) {
        int y = (t >= off) ? s[t - off] : 0;
        __syncthreads();
        s[t] += y;
        __syncthreads();
    }
    if (t < SCAN_BLOCKS) bsums[t] = s[t] - v;
}

__global__ __launch_bounds__(256) void scan3_kernel(int* __restrict__ rowstart,
                                                    const int* __restrict__ bsums) {
    const int t = threadIdx.x;
    const int base = blockIdx.x * 1024 + t * 4;
    const int add = bsums[blockIdx.x];
#pragma unroll
    for (int r = 0; r < 4; ++r)
        if (base + r < N_NODES) rowstart[base + r] += add;
}

__global__ __launch_bounds__(256) void scatter_kernel(const int* __restrict__ esrc,
                                                      const int* __restrict__ edst,
                                                      const float* __restrict__ evals,
                                                      const int* __restrict__ rowstart,
                                                      int* __restrict__ cursor,
                                                      int2* __restrict__ sorted_edges) {
    const int e = blockIdx.x * 256 + threadIdx.x;
    const int d = edst[e];
    const int p = rowstart[d] + atomicAdd(&cursor[d], 1);
    sorted_edges[p] = make_int2(esrc[e], __float_as_int(evals[e]));
}

// ---------------------------------------------------------------------------
// K2 fused: per dst node (one wave): h = relu(sum_e w*support1[src] + b1),
// support2[node] = h @ W2 (f16 out).  16-edge ILP batches (w=0 padding).
// ---------------------------------------------------------------------------
__global__ __launch_bounds__(256) void spmm1_fused_kernel(const int* __restrict__ rowstart,
                                                          const int* __restrict__ deg,
                                                          const int2* __restrict__ sorted_edges,
                                                          const _Float16* __restrict__ support1,
                                                          const float* __restrict__ b1,
                                                          const float* __restrict__ W2,
                                                          _Float16* __restrict__ support2) {
    __shared__ float W2s[64 * 16];
    __shared__ float b1s[64];
    __shared__ float hs[4][64];
    const int t = threadIdx.x;
#pragma unroll
    for (int i = 0; i < 4; ++i) W2s[t + i * 256] = W2[t + i * 256];
    if (t < 64) b1s[t] = b1[t];
    __syncthreads();

    const int wave = t >> 6;
    const int lane = t & 63;
    const int node = blockIdx.x * 4 + wave;   // grid exact: 25000*4

    const int beg = rowstart[node];
    const int cnt = deg[node];

    int   src_l = 0;
    float val_l = 0.f;
    if (lane < cnt) {
        int2 ev = sorted_edges[beg + lane];
        src_l = ev.x;
        val_l = __int_as_float(ev.y);
    }

    float acc = 0.f;
    const int kmax = cnt < 64 ? cnt : 64;
    const int kr   = (kmax + 15) & ~15;       // pad batches: w=0 slots are no-ops
    for (int k = 0; k < kr; k += 16) {
        float f[16], w[16];
#pragma unroll
        for (int u = 0; u < 16; ++u) {
            int s = __shfl(src_l, k + u);
            w[u]  = __shfl(val_l, k + u);
            f[u]  = (float)support1[(size_t)s * F_HID + lane];
        }
#pragma unroll
        for (int u = 0; u < 16; ++u) acc = fmaf(w[u], f[u], acc);
    }
    for (int k = 64; k < cnt; ++k) {          // vanishingly rare (Poisson 16)
        int2 ev = sorted_edges[beg + k];
        acc = fmaf(__int_as_float(ev.y),
                   (float)support1[(size_t)ev.x * F_HID + lane], acc);
    }

    hs[wave][lane] = fmaxf(acc + b1s[lane], 0.f);
    __syncthreads();

    if (lane < 16) {
        float o = 0.f;
#pragma unroll
        for (int kk = 0; kk < 64; ++kk)
            o = fmaf(hs[wave][kk], W2s[kk * 16 + lane], o);
        support2[(size_t)node * F_OUT + lane] = (_Float16)o;
    }
}

// ---------------------------------------------------------------------------
// K3 fused: per dst node (16 lanes): logits = sum_e w*support2[src] + b2,
// then log_softmax.  8-edge ILP batches.
// ---------------------------------------------------------------------------
__global__ __launch_bounds__(256) void spmm2_fused_kernel(const int* __restrict__ rowstart,
                                                          const int* __restrict__ deg,
                                                          const int2* __restrict__ sorted_edges,
                                                          const _Float16* __restrict__ support2,
                                                          const float* __restrict__ b2,
                                                          float* __restrict__ out) {
    __shared__ float b2s[16];
    const int t = threadIdx.x;
    if (t < 16) b2s[t] = b2[t];
    __syncthreads();

    const int j    = t & 15;
    const int node = blockIdx.x * 16 + (t >> 4);   // grid exact: 6250*16

    const int beg = rowstart[node];
    const int cnt = deg[node];

    int   src_a = 0, src_b = 0;
    float val_a = 0.f, val_b = 0.f;
    if (j < cnt)      { int2 ev = sorted_edges[beg + j];      src_a = ev.x; val_a = __int_as_float(ev.y); }
    if (j + 16 < cnt) { int2 ev = sorted_edges[beg + 16 + j]; src_b = ev.x; val_b = __int_as_float(ev.y); }

    float acc = 0.f;
    const int kmax2 = cnt < 32 ? cnt : 32;
    int k = 0;
    for (; k + 8 <= kmax2; k += 8) {
        float f[8], w[8];
#pragma unroll
        for (int u = 0; u < 8; ++u) {
            int kk = k + u;
            int   s = (k < 16) ? __shfl(src_a, kk, 16) : __shfl(src_b, kk - 16, 16);
            w[u]    = (k < 16) ? __shfl(val_a, kk, 16) : __shfl(val_b, kk - 16, 16);
            f[u]    = (float)support2[(size_t)s * F_OUT + j];
        }
#pragma unroll
        for (int u = 0; u < 8; ++u) acc = fmaf(w[u], f[u], acc);
    }
    for (; k < kmax2; ++k) {
        int   s = (k < 16) ? __shfl(src_a, k, 16) : __shfl(src_b, k - 16, 16);
        float w = (k < 16) ? __shfl(val_a, k, 16) : __shfl(val_b, k - 16, 16);
        acc = fmaf(w, (float)support2[(size_t)s * F_OUT + j], acc);
    }
    for (k = 32; k < cnt; ++k) {
        int2 ev = sorted_edges[beg + k];
        acc = fmaf(__int_as_float(ev.y),
                   (float)support2[(size_t)ev.x * F_OUT + j], acc);
    }

    float v = acc + b2s[j];
    float m = v;
#pragma unroll
    for (int off = 8; off > 0; off >>= 1)
        m = fmaxf(m, __shfl_xor(m, off, 16));
    float ex = __expf(v - m);
    float sum = ex;
#pragma unroll
    for (int off = 8; off > 0; off >>= 1)
        sum += __shfl_xor(sum, off, 16);
    out[(size_t)node * F_OUT + j] = v - m - __logf(sum);
}

// ---------------------------------------------------------------------------
extern "C" void kernel_launch(void* const* d_in, const int* in_sizes, int n_in,
                              void* d_out, int out_size, void* d_ws, size_t ws_size,
                              hipStream_t stream) {
    const float* x     = (const float*)d_in[0];
    const int*   esrc  = (const int*)  d_in[1];
    const int*   edst  = (const int*)  d_in[2];
    const float* evals = (const float*)d_in[3];
    const float* W1    = (const float*)d_in[4];
    const float* b1    = (const float*)d_in[5];
    const float* W2    = (const float*)d_in[6];
    const float* b2    = (const float*)d_in[7];
    float* out = (float*)d_out;

    // Workspace layout (~30 MB); all segment offsets 16 B-aligned.
    _Float16* support1     = (_Float16*)d_ws;                              // N*64 f16
    _Float16* support2     = support1 + (size_t)N_NODES * F_HID;           // N*16 f16
    int2*     sorted_edges = (int2*)(support2 + (size_t)N_NODES * F_OUT);  // E int2
    int*      rowstart     = (int*)(sorted_edges + E_EDGES);               // N
    int*      deg          = rowstart + N_NODES;                           // N (hist/cursor)
    int*      bsums        = deg + N_NODES;                                // 128
    _Float16* w1sw         = (_Float16*)(bsums + 128);                     // 16384 f16

    hipMemsetAsync(deg, 0, (size_t)N_NODES * sizeof(int), stream);
    w1_swizzle_kernel<<<64, 256, 0, stream>>>(W1, w1sw);
    gemm1_hist_kernel<<<GEMM1_BLOCKS + HIST_BLOCKS, 256, 0, stream>>>(x, w1sw, support1, edst, deg);
    scan1_kernel<<<SCAN_BLOCKS, 256, 0, stream>>>(deg, rowstart, bsums);
    scan2_kernel<<<1, 128, 0, stream>>>(bsums);
    scan3_kernel<<<SCAN_BLOCKS, 256, 0, stream>>>(rowstart, bsums);
    hipMemsetAsync(deg, 0, (size_t)N_NODES * sizeof(int), stream);
    scatter_kernel<<<E_EDGES / 256, 256, 0, stream>>>(esrc, edst, evals, rowstart, deg,
                                                      sorted_edges);
    spmm1_fused_kernel<<<N_NODES / 4, 256, 0, stream>>>(rowstart, deg, sorted_edges,
                                                        support1, b1, W2, support2);
    spmm2_fused_kernel<<<N_NODES / 16, 256, 0, stream>>>(rowstart, deg, sorted_edges,
                                                         support2, b2, out);
}

// Round 5
// 359.868 us; speedup vs baseline: 5.3320x; 1.1823x over previous
//
#include <hip/hip_runtime.h>
#include <hip/hip_fp16.h>

#define N_NODES 100000
#define E_EDGES 1600000
#define F_IN    256
#define F_HID   64
#define F_OUT   16
#define NBKT    98            // buckets of 1024 dst-nodes (99999>>10 = 97)
#define W1SW_BLOCKS  64
#define AHIST_BLOCKS 1563     // ceil(E/1024)
#define GEMM1_BLOCKS 782      // ceil(N/128)

typedef _Float16 half8   __attribute__((ext_vector_type(8)));
typedef float    floatx4 __attribute__((ext_vector_type(4)));

// ---------------------------------------------------------------------------
// Prep (fused): blocks [0,64): swizzle W1 -> f16 MFMA B-frag order.
// blocks [64,..): coarse bucket histogram of edge dst (LDS hist, 98 global
// atomics per 1024-edge block).
// ---------------------------------------------------------------------------
__global__ __launch_bounds__(256) void prep_kernel(const float* __restrict__ W1,
                                                   _Float16* __restrict__ w1sw,
                                                   const int* __restrict__ edst,
                                                   int* __restrict__ bucketCount) {
    const int t = threadIdx.x;
    if (blockIdx.x < W1SW_BLOCKS) {
        const int i = blockIdx.x * 256 + t;   // 16384
        const int k = i >> 6, n = i & 63;
        const int kb = k >> 5, quad = (k >> 3) & 3, j = k & 7;
        const int nt = n >> 4, ln = n & 15;
        w1sw[((size_t)((kb * 4 + nt) * 64 + quad * 16 + ln)) * 8 + j] = (_Float16)W1[i];
        return;
    }
    __shared__ int hist[128];
    const int blk = blockIdx.x - W1SW_BLOCKS;
    if (t < NBKT) hist[t] = 0;
    __syncthreads();
    const int e0 = blk * 1024 + t * 4;
    if (e0 < E_EDGES) {
        int4 d4 = *(const int4*)&edst[e0];
        atomicAdd(&hist[d4.x >> 10], 1);
        atomicAdd(&hist[d4.y >> 10], 1);
        atomicAdd(&hist[d4.z >> 10], 1);
        atomicAdd(&hist[d4.w >> 10], 1);
    }
    __syncthreads();
    if (t < NBKT) atomicAdd(&bucketCount[t], hist[t]);
}

// ---------------------------------------------------------------------------
// Exclusive scan of 98 bucket counts -> bucketStart; init bucketCursor.
// ---------------------------------------------------------------------------
__global__ __launch_bounds__(128) void bucket_scan_kernel(const int* __restrict__ bucketCount,
                                                          int* __restrict__ bucketStart,
                                                          int* __restrict__ bucketCursor) {
    __shared__ int s[128];
    const int t = threadIdx.x;
    int v = (t < NBKT) ? bucketCount[t] : 0;
    s[t] = v;
    __syncthreads();
#pragma unroll
    for (int off = 1; off < 128; off <<= 1) {
        int y = (t >= off) ? s[t - off] : 0;
        __syncthreads();
        s[t] += y;
        __syncthreads();
    }
    if (t < NBKT) { bucketStart[t] = s[t] - v; bucketCursor[t] = s[t] - v; }
}

// ---------------------------------------------------------------------------
// K1 (fused): blocks [0,GEMM1_BLOCKS): support1 = x @ W1 via MFMA f16.
// Blocks after that: pass A of the bucket sort — write packed records
// (dstLocal<<17 | src, val) into bucket regions (dense, L2-friendly).
// ---------------------------------------------------------------------------
__global__ __launch_bounds__(256) void gemm1_passA_kernel(const float* __restrict__ x,
                                                          const _Float16* __restrict__ w1sw,
                                                          _Float16* __restrict__ support1,
                                                          const int* __restrict__ esrc,
                                                          const int* __restrict__ edst,
                                                          const float* __restrict__ evals,
                                                          int* __restrict__ bucketCursor,
                                                          int2* __restrict__ tmp) {
    __shared__ __align__(16) char ldsbuf[32768];
    const int t = threadIdx.x;

    if (blockIdx.x >= GEMM1_BLOCKS) {
        // ---- pass A ----
        int* hist = (int*)ldsbuf;          // 128 ints
        int* base = (int*)ldsbuf + 128;    // 128 ints
        const int blk = blockIdx.x - GEMM1_BLOCKS;
        if (t < NBKT) hist[t] = 0;
        __syncthreads();
        const int e0 = blk * 1024 + t * 4;
        const bool ok = e0 < E_EDGES;
        int dd[4], ss[4], bu[4], rk[4];
        float vv[4];
        if (ok) {
            int4 d4 = *(const int4*)&edst[e0];
            int4 s4 = *(const int4*)&esrc[e0];
            float4 v4 = *(const float4*)&evals[e0];
            dd[0] = d4.x; dd[1] = d4.y; dd[2] = d4.z; dd[3] = d4.w;
            ss[0] = s4.x; ss[1] = s4.y; ss[2] = s4.z; ss[3] = s4.w;
            vv[0] = v4.x; vv[1] = v4.y; vv[2] = v4.z; vv[3] = v4.w;
#pragma unroll
            for (int u = 0; u < 4; ++u) {
                bu[u] = dd[u] >> 10;
                rk[u] = atomicAdd(&hist[bu[u]], 1);
            }
        }
        __syncthreads();
        if (t < NBKT) base[t] = atomicAdd(&bucketCursor[t], hist[t]);
        __syncthreads();
        if (ok) {
#pragma unroll
            for (int u = 0; u < 4; ++u) {
                int pos = base[bu[u]] + rk[u];
                tmp[pos] = make_int2(((dd[u] & 1023) << 17) | ss[u],
                                     __float_as_int(vv[u]));
            }
        }
        return;
    }

    // ---- MFMA gemm1 ----
    _Float16* Bs = (_Float16*)ldsbuf;   // 32 KB, frag-ordered
    {
        const float4* srcv = (const float4*)w1sw;
        float4*       dstv = (float4*)Bs;
#pragma unroll
        for (int i = 0; i < 8; ++i) dstv[t + i * 256] = srcv[t + i * 256];
    }
    __syncthreads();

    const int wave = t >> 6;
    const int lane = t & 63;
    const int ln   = lane & 15;
    const int quad = lane >> 4;
    const int row0 = blockIdx.x * 128 + wave * 32;

    const float* xp[2];
#pragma unroll
    for (int mt = 0; mt < 2; ++mt) {
        int r = row0 + mt * 16 + ln;
        if (r > N_NODES - 1) r = N_NODES - 1;
        xp[mt] = x + (size_t)r * F_IN + quad * 8;
    }

    floatx4 acc[2][4] = {};

#pragma unroll 4
    for (int kb = 0; kb < 8; ++kb) {
        half8 a[2];
#pragma unroll
        for (int mt = 0; mt < 2; ++mt) {
            float4 v0 = *(const float4*)(xp[mt] + kb * 32);
            float4 v1 = *(const float4*)(xp[mt] + kb * 32 + 4);
            half8 h;
            h[0] = (_Float16)v0.x; h[1] = (_Float16)v0.y;
            h[2] = (_Float16)v0.z; h[3] = (_Float16)v0.w;
            h[4] = (_Float16)v1.x; h[5] = (_Float16)v1.y;
            h[6] = (_Float16)v1.z; h[7] = (_Float16)v1.w;
            a[mt] = h;
        }
#pragma unroll
        for (int nt = 0; nt < 4; ++nt) {
            half8 b = *(const half8*)&Bs[((size_t)((kb * 4 + nt) * 64 + lane)) * 8];
            acc[0][nt] = __builtin_amdgcn_mfma_f32_16x16x32_f16(a[0], b, acc[0][nt], 0, 0, 0);
            acc[1][nt] = __builtin_amdgcn_mfma_f32_16x16x32_f16(a[1], b, acc[1][nt], 0, 0, 0);
        }
    }

#pragma unroll
    for (int mt = 0; mt < 2; ++mt) {
        const int rbase = row0 + mt * 16 + quad * 4;
#pragma unroll
        for (int r = 0; r < 4; ++r) {
            const int row = rbase + r;
            if (row < N_NODES) {
#pragma unroll
                for (int nt = 0; nt < 4; ++nt)
                    support1[(size_t)row * F_HID + nt * 16 + ln] = (_Float16)acc[mt][nt][r];
            }
        }
    }
}

// ---------------------------------------------------------------------------
// Pass B: one block per bucket. LDS degree hist + scan + cursors; final
// scatter within a ~131 KB L2-resident window. Emits rowstart/deg directly.
// ---------------------------------------------------------------------------
__global__ __launch_bounds__(256) void passB_kernel(const int2* __restrict__ tmp,
                                                    const int* __restrict__ bucketStart,
                                                    const int* __restrict__ bucketCount,
                                                    int2* __restrict__ sorted_edges,
                                                    int* __restrict__ rowstart,
                                                    int* __restrict__ deg) {
    __shared__ int ldeg[1024];
    __shared__ int lcur[1024];
    __shared__ int s[256];
    const int t = threadIdx.x;
    const int b = blockIdx.x;
    const int node0 = b << 10;
    const int beg = bucketStart[b];
    const int cnt = bucketCount[b];

#pragma unroll
    for (int i = 0; i < 4; ++i) ldeg[t + i * 256] = 0;
    __syncthreads();

    for (int p = beg + t; p < beg + cnt; p += 256) {
        int2 r = tmp[p];
        atomicAdd(&ldeg[r.x >> 17], 1);
    }
    __syncthreads();

    // exclusive scan of ldeg[1024]: 4 per thread + Hillis-Steele over 256.
    int v[4], sum = 0;
#pragma unroll
    for (int r = 0; r < 4; ++r) { v[r] = ldeg[t * 4 + r]; sum += v[r]; }
    s[t] = sum;
    __syncthreads();
#pragma unroll
    for (int off = 1; off < 256; off <<= 1) {
        int y = (t >= off) ? s[t - off] : 0;
        __syncthreads();
        s[t] += y;
        __syncthreads();
    }
    int run = s[t] - sum;
#pragma unroll
    for (int r = 0; r < 4; ++r) {
        const int i = t * 4 + r;
        lcur[i] = run;
        const int node = node0 + i;
        if (node < N_NODES) { rowstart[node] = beg + run; deg[node] = v[r]; }
        run += v[r];
    }
    __syncthreads();

    for (int p = beg + t; p < beg + cnt; p += 256) {
        int2 r = tmp[p];
        const int dl  = r.x >> 17;
        const int pos = beg + atomicAdd(&lcur[dl], 1);
        sorted_edges[pos] = make_int2(r.x & 0x1FFFF, r.y);
    }
}

// ---------------------------------------------------------------------------
// K2 fused: per dst node (one wave): h = relu(sum_e w*support1[src] + b1),
// support2[node] = h @ W2 (f16 out).  16-edge ILP batches; full-wave epilogue.
// ---------------------------------------------------------------------------
__global__ __launch_bounds__(256) void spmm1_fused_kernel(const int* __restrict__ rowstart,
                                                          const int* __restrict__ deg,
                                                          const int2* __restrict__ sorted_edges,
                                                          const _Float16* __restrict__ support1,
                                                          const float* __restrict__ b1,
                                                          const float* __restrict__ W2,
                                                          _Float16* __restrict__ support2) {
    __shared__ float W2s[64 * 16];
    __shared__ float b1s[64];
    __shared__ float hs[4][64];
    const int t = threadIdx.x;
#pragma unroll
    for (int i = 0; i < 4; ++i) W2s[t + i * 256] = W2[t + i * 256];
    if (t < 64) b1s[t] = b1[t];
    __syncthreads();

    const int wave = t >> 6;
    const int lane = t & 63;
    const int node = blockIdx.x * 4 + wave;   // grid exact: 25000*4

    const int beg = rowstart[node];
    const int cnt = deg[node];

    int   src_l = 0;
    float val_l = 0.f;
    if (lane < cnt) {
        int2 ev = sorted_edges[beg + lane];
        src_l = ev.x;
        val_l = __int_as_float(ev.y);
    }

    float acc = 0.f;
    const int kmax = cnt < 64 ? cnt : 64;
    const int kr   = (kmax + 15) & ~15;
    for (int k = 0; k < kr; k += 16) {
        float f[16], w[16];
#pragma unroll
        for (int u = 0; u < 16; ++u) {
            int s2 = __shfl(src_l, k + u);
            w[u]   = __shfl(val_l, k + u);
            f[u]   = (float)support1[(size_t)s2 * F_HID + lane];
        }
#pragma unroll
        for (int u = 0; u < 16; ++u) acc = fmaf(w[u], f[u], acc);
    }
    for (int k = 64; k < cnt; ++k) {          // vanishingly rare (Poisson 16)
        int2 ev = sorted_edges[beg + k];
        acc = fmaf(__int_as_float(ev.y),
                   (float)support1[(size_t)ev.x * F_HID + lane], acc);
    }

    hs[wave][lane] = fmaxf(acc + b1s[lane], 0.f);
    __syncthreads();

    // full-wave h @ W2: lane = (quad k-segment, ln out-col); reduce across quads.
    const int ln   = lane & 15;
    const int quad = lane >> 4;
    float o = 0.f;
#pragma unroll
    for (int kk = 0; kk < 16; ++kk) {
        const int k2 = quad * 16 + kk;
        o = fmaf(hs[wave][k2], W2s[k2 * 16 + ln], o);
    }
    o += __shfl_xor(o, 16);
    o += __shfl_xor(o, 32);
    if (quad == 0)
        support2[(size_t)node * F_OUT + ln] = (_Float16)o;
}

// ---------------------------------------------------------------------------
// K3 fused: per dst node (16 lanes): logits = sum_e w*support2[src] + b2,
// then log_softmax.
// ---------------------------------------------------------------------------
__global__ __launch_bounds__(256) void spmm2_fused_kernel(const int* __restrict__ rowstart,
                                                          const int* __restrict__ deg,
                                                          const int2* __restrict__ sorted_edges,
                                                          const _Float16* __restrict__ support2,
                                                          const float* __restrict__ b2,
                                                          float* __restrict__ out) {
    __shared__ float b2s[16];
    const int t = threadIdx.x;
    if (t < 16) b2s[t] = b2[t];
    __syncthreads();

    const int j    = t & 15;
    const int node = blockIdx.x * 16 + (t >> 4);   // grid exact: 6250*16

    const int beg = rowstart[node];
    const int cnt = deg[node];

    int   src_a = 0, src_b = 0;
    float val_a = 0.f, val_b = 0.f;
    if (j < cnt)      { int2 ev = sorted_edges[beg + j];      src_a = ev.x; val_a = __int_as_float(ev.y); }
    if (j + 16 < cnt) { int2 ev = sorted_edges[beg + 16 + j]; src_b = ev.x; val_b = __int_as_float(ev.y); }

    float acc = 0.f;
    const int kmax2 = cnt < 32 ? cnt : 32;
    int k = 0;
    for (; k + 8 <= kmax2; k += 8) {
        float f[8], w[8];
#pragma unroll
        for (int u = 0; u < 8; ++u) {
            int kk = k + u;
            int   s2 = (k < 16) ? __shfl(src_a, kk, 16) : __shfl(src_b, kk - 16, 16);
            w[u]     = (k < 16) ? __shfl(val_a, kk, 16) : __shfl(val_b, kk - 16, 16);
            f[u]     = (float)support2[(size_t)s2 * F_OUT + j];
        }
#pragma unroll
        for (int u = 0; u < 8; ++u) acc = fmaf(w[u], f[u], acc);
    }
    for (; k < kmax2; ++k) {
        int   s2 = (k < 16) ? __shfl(src_a, k, 16) : __shfl(src_b, k - 16, 16);
        float w  = (k < 16) ? __shfl(val_a, k, 16) : __shfl(val_b, k - 16, 16);
        acc = fmaf(w, (float)support2[(size_t)s2 * F_OUT + j], acc);
    }
    for (k = 32; k < cnt; ++k) {
        int2 ev = sorted_edges[beg + k];
        acc = fmaf(__int_as_float(ev.y),
                   (float)support2[(size_t)ev.x * F_OUT + j], acc);
    }

    float v = acc + b2s[j];
    float m = v;
#pragma unroll
    for (int off = 8; off > 0; off >>= 1)
        m = fmaxf(m, __shfl_xor(m, off, 16));
    float ex = __expf(v - m);
    float sum = ex;
#pragma unroll
    for (int off = 8; off > 0; off >>= 1)
        sum += __shfl_xor(sum, off, 16);
    out[(size_t)node * F_OUT + j] = v - m - __logf(sum);
}

// ---------------------------------------------------------------------------
extern "C" void kernel_launch(void* const* d_in, const int* in_sizes, int n_in,
                              void* d_out, int out_size, void* d_ws, size_t ws_size,
                              hipStream_t stream) {
    const float* x     = (const float*)d_in[0];
    const int*   esrc  = (const int*)  d_in[1];
    const int*   edst  = (const int*)  d_in[2];
    const float* evals = (const float*)d_in[3];
    const float* W1    = (const float*)d_in[4];
    const float* b1    = (const float*)d_in[5];
    const float* W2    = (const float*)d_in[6];
    const float* b2    = (const float*)d_in[7];
    float* out = (float*)d_out;

    // Workspace layout (~42.5 MB); all segments 16 B-aligned.
    _Float16* support1     = (_Float16*)d_ws;                              // N*64 f16
    _Float16* support2     = support1 + (size_t)N_NODES * F_HID;           // N*16 f16
    int2*     tmp          = (int2*)(support2 + (size_t)N_NODES * F_OUT);  // E int2
    int2*     sorted_edges = tmp + E_EDGES;                                // E int2
    int*      rowstart     = (int*)(sorted_edges + E_EDGES);               // N
    int*      deg          = rowstart + N_NODES;                           // N
    int*      bucketCount  = deg + N_NODES;                                // 128
    int*      bucketStart  = bucketCount + 128;                            // 128
    int*      bucketCursor = bucketStart + 128;                            // 128
    _Float16* w1sw         = (_Float16*)(bucketCursor + 128);              // 16384 f16

    hipMemsetAsync(bucketCount, 0, 128 * sizeof(int), stream);
    prep_kernel<<<W1SW_BLOCKS + AHIST_BLOCKS, 256, 0, stream>>>(W1, w1sw, edst, bucketCount);
    bucket_scan_kernel<<<1, 128, 0, stream>>>(bucketCount, bucketStart, bucketCursor);
    gemm1_passA_kernel<<<GEMM1_BLOCKS + AHIST_BLOCKS, 256, 0, stream>>>(
        x, w1sw, support1, esrc, edst, evals, bucketCursor, tmp);
    passB_kernel<<<NBKT, 256, 0, stream>>>(tmp, bucketStart, bucketCount,
                                           sorted_edges, rowstart, deg);
    spmm1_fused_kernel<<<N_NODES / 4, 256, 0, stream>>>(rowstart, deg, sorted_edges,
                                                        support1, b1, W2, support2);
    spmm2_fused_kernel<<<N_NODES / 16, 256, 0, stream>>>(rowstart, deg, sorted_edges,
                                                         support2, b2, out);
}